// Round 1
// 338.040 us; speedup vs baseline: 1.3108x; 1.3108x over previous
//
#include <hip/hip_runtime.h>
#include <hip/hip_bf16.h>
#include <math.h>

#define NB   16
#define CIN  128
#define COUT 128
#define HH   56
#define WW   56
#define LL   3136

typedef __attribute__((ext_vector_type(8))) short short8;
typedef __attribute__((ext_vector_type(16))) float f32x16;
typedef __attribute__((ext_vector_type(4))) float f32x4;
typedef __attribute__((ext_vector_type(4))) unsigned int uint4v;

// ---- mfma geometry ----
#define PXT    256            // pixels per block (linear)
#define NPXT   13             // ceil(3136/256)
#define XC     58             // cols incl halo
#define XRR    8              // rows incl halo (256px spans <=6 rows +2)
#define QN     (XRR*XC)       // 464 pixel slots
#define XPLANE 7424           // ushorts per x plane (QN*16)
#define XUSH   14848          // ushorts x total (hi+lo)
#define XUNITS 1856           // 16B units in x region
#define XHALF  928            // units per plane
#define CPW    16             // weight row pitch (ushorts)
#define WS_TAP 1024           // ushorts per tap per plane (64 rows * 16)
#define WS_N   9216           // ushorts per plane (9 taps)
#define WUSH   18432          // ushorts w total (hi+lo)
#define WBYTES 36864
#define SMUSH  (XUSH + WUSH)  // 33280 ushorts = 66560 B

// xt layout: [cg 8][bat 16][plane 2][row 62][col 58][16ch] ushorts (halo rows/cols zero)
#define XT_ROWS 62
#define XT_PLANE_USH (XT_ROWS*XC*16)   // 57536
#define XT_CG_STRIDE 3682304           // bytes per cg slab (16*2*62*58*32)

// ---- workspace layout (bytes) ----
#define CSD_OFF 256
#define WSP_OFF 32768
#define XT_OFF  1212416
#define XT_SIZE 29458432
#define WL_OFF  (XT_OFF + XT_SIZE)     // 30,670,848  (needs ws_size >= ~31MB)

// ---------------- prep: fp64 cos/sin table ----------------
__global__ void prep_csd_kernel(const float* __restrict__ bk, double* __restrict__ csd) {
    int i = blockIdx.x * 256 + threadIdx.x;
    if (i < 2*9*COUT) {
        int s = i / (9*COUT);
        int rem = i - s*(9*COUT);
        double v = (double)bk[rem];
        csd[i] = (s == 0) ? cos(v) : sin(v);
    }
}

// ---------------- prep: folded/split weights, pre-swizzled LDS image ----------------
// wsp layout: [ocb 4][cg 8] images of WBYTES; image = [plane 2][tap 9][row 64][16 ush]
__global__ void prep_w_kernel(const float* __restrict__ w, const double* __restrict__ csd,
                              unsigned short* __restrict__ wsp) {
    int i = blockIdx.x * 256 + threadIdx.x;
    if (i >= 9*COUT*CIN) return;
    int k = i / (COUT*CIN);
    int rem = i - k*(COUT*CIN);
    int oc = rem >> 7, c = rem & 127;
    double ck = csd[k*COUT + oc];
    double sk = csd[9*COUT + k*COUT + oc];
    float wv = w[i];
    float fa = (float)(ck * (double)wv);
    float fb = (float)(sk * (double)wv);
    __hip_bfloat16 ah = __float2bfloat16(fa);
    __hip_bfloat16 al = __float2bfloat16(fa - __bfloat162float(ah));
    __hip_bfloat16 bh = __float2bfloat16(fb);
    __hip_bfloat16 bl = __float2bfloat16(fb - __bfloat162float(bh));
    int ocb = oc >> 5;
    int rowa = oc & 31, rowb = 32 + rowa;
    int cg = c >> 4, cp = c & 15;
    int sl = (((cp >> 3) ^ ((rowa >> 2) & 1)) << 3) | (cp & 7);   // xor-swizzled 8-slot
    size_t img = ((size_t)ocb*8 + cg) * WUSH;
    wsp[img + (size_t)k*WS_TAP + rowa*CPW + sl]        = *(unsigned short*)&ah;
    wsp[img + (size_t)k*WS_TAP + rowb*CPW + sl]        = *(unsigned short*)&bh;
    wsp[img + WS_N + (size_t)k*WS_TAP + rowa*CPW + sl] = *(unsigned short*)&al;
    wsp[img + WS_N + (size_t)k*WS_TAP + rowb*CPW + sl] = *(unsigned short*)&bl;
}

// ---------------- prep: x -> bf16 hi/lo transposed padded layout ----------------
__global__ void prep_x_kernel(const float* __restrict__ x, unsigned short* __restrict__ xt) {
    int i = blockIdx.x * 256 + threadIdx.x;      // 1798*256 = 460288 exact
    int c58 = i % XC;
    int t = i / XC;
    int row = t % XT_ROWS;
    t /= XT_ROWS;
    int bat = t & 15;
    int cg  = t >> 4;                            // 0..7
    int gr = row - 1, gc = c58 - 1;
    bool valid = ((unsigned)gr < HH) && ((unsigned)gc < WW);
    unsigned short hi[16], lo[16];
    #pragma unroll
    for (int j = 0; j < 16; j++) {
        float v = 0.f;
        if (valid) v = x[(size_t)(bat*CIN + cg*16 + j)*LL + gr*WW + gc];
        __hip_bfloat16 h = __float2bfloat16(v);
        __hip_bfloat16 l = __float2bfloat16(v - __bfloat162float(h));
        hi[j] = *(unsigned short*)&h;
        lo[j] = *(unsigned short*)&l;
    }
    size_t base = ((((size_t)cg*16 + bat)*2 + 0)*XT_ROWS + row)*XC + c58;   // 32B units
    unsigned short* dh = xt + base*16;
    unsigned short* dl = dh + XT_PLANE_USH;
    *(uint4v*)dh       = *(const uint4v*)&hi[0];
    *(uint4v*)(dh + 8) = *(const uint4v*)&hi[8];
    *(uint4v*)dl       = *(const uint4v*)&lo[0];
    *(uint4v*)(dl + 8) = *(const uint4v*)&lo[8];
}

// ---------------- main MFMA kernel ----------------
__global__ __launch_bounds__(256, 2)
void mfma_kernel(const unsigned short* __restrict__ xt, const unsigned short* __restrict__ wsp,
                 const float* __restrict__ bias, float* __restrict__ out,
                 unsigned* __restrict__ cnt, unsigned* __restrict__ wl, unsigned cap)
{
    __shared__ __align__(16) unsigned short SM[SMUSH];   // x: [0,XUSH) hi|lo ; w: [XUSH,SMUSH)
    __shared__ float sm_bias[32];

    const int tid = threadIdx.x;
    // XCD-chunked bijective swizzle: 4 ocb siblings + neighbor tiles share an XCD L2
    int bid = blockIdx.x;
    int wk = (bid & 7) * (NB*NPXT*4/8) + (bid >> 3);
    const int ocb = wk & 3; wk >>= 2;
    const int pxt = wk % NPXT;
    const int bat = wk / NPXT;
    const int l0  = pxt * PXT;
    const int o0  = ocb * 32;
    const int yf  = l0 / WW;

    const int lane = tid & 63;
    const int n    = lane & 31;
    const int kh   = lane >> 5;
    const int wave = tid >> 6;

    if (tid < 32) sm_bias[tid] = bias[o0 + tid];

    // per-thread staging source offsets (bytes within one cg-slab of xt), chunk-invariant
    unsigned xoff[8];
    #pragma unroll
    for (int k = 0; k < 8; k++) {
        int u = tid + 256*k;
        int uc = u < XUNITS ? u : XUNITS-1;      // dummies clamp (their ds_write is skipped)
        int pl = uc >= XHALF ? 1 : 0;
        int rem = uc - pl*XHALF;
        int q  = rem >> 1;
        int hl = rem & 1;
        int hg = hl ^ ((q >> 2) & 1);            // inverse of read-side bank swizzle
        int r  = q / XC;
        int c  = q - r*XC;
        xoff[k] = (unsigned)((((bat*2 + pl)*XT_ROWS + (yf + r))*XC + c)*32 + hg*16);
    }

    // B-frag pixel slots (2 groups per wave)
    int q0g[2];
    #pragma unroll
    for (int g = 0; g < 2; g++) {
        int p  = l0 + wave*64 + g*32 + n;
        int pc = p < LL ? p : LL-1;
        int py = pc / WW, pxx = pc - py*WW;
        q0g[g] = (py - yf)*XC + pxx;
    }
    const int sw  = ((((n>>2)&1) ^ kh) << 3);
    const int iAa = n*CPW + sw;
    const int iAb = (32+n)*CPW + sw;

    f32x16 acc_a[2], acc_b[2];
    #pragma unroll
    for (int g = 0; g < 2; g++) {
        #pragma unroll
        for (int r = 0; r < 16; r++) { acc_a[g][r] = 0.f; acc_b[g][r] = 0.f; }
    }

    const char* xtB  = (const char*)xt;
    const char* wspB = (const char*)wsp + (size_t)ocb * (8*WBYTES);

    uint4v xpf[8], wpf[9];

    auto load_stage = [&](int chn) {
        const char* xp = xtB + (size_t)chn * XT_CG_STRIDE;
        #pragma unroll
        for (int k = 0; k < 8; k++) xpf[k] = *(const uint4v*)(xp + xoff[k]);
        const char* wp = wspB + (size_t)chn * WBYTES + tid*16;
        #pragma unroll
        for (int k = 0; k < 9; k++) wpf[k] = *(const uint4v*)(wp + k*4096);
    };
    auto write_stage = [&]() {
        #pragma unroll
        for (int k = 0; k < 7; k++) *(uint4v*)&SM[(tid + 256*k)*8] = xpf[k];
        if (tid < (XUNITS - 1792)) *(uint4v*)&SM[(tid + 1792)*8] = xpf[7];
        #pragma unroll
        for (int k = 0; k < 9; k++) *(uint4v*)&SM[XUSH + (tid + 256*k)*8] = wpf[k];
    };

    // prologue: stage chunk 0, prefetch chunk 1
    load_stage(0);
    write_stage();
    __syncthreads();
    load_stage(1);

    #pragma unroll 1
    for (int ch = 0; ch < 8; ch++) {
        #pragma unroll
        for (int tap = 0; tap < 9; tap++) {
            const int ky = tap / 3, kx = tap - 3*ky;
            const int wb = XUSH + tap*WS_TAP;
            short8 Aha = *(const short8*)&SM[wb + iAa];
            short8 Ahb = *(const short8*)&SM[wb + iAb];
            short8 Ala = *(const short8*)&SM[wb + WS_N + iAa];
            short8 Alb = *(const short8*)&SM[wb + WS_N + iAb];
            #pragma unroll
            for (int g = 0; g < 2; g++) {
                int q  = q0g[g] + ky*XC + kx;
                int si = q*16 + ((kh ^ ((q>>2)&1)) << 3);
                short8 Bh = *(const short8*)&SM[si];
                short8 Bl = *(const short8*)&SM[XPLANE + si];
                acc_a[g] = __builtin_amdgcn_mfma_f32_32x32x16_bf16(Ala, Bh, acc_a[g], 0,0,0);
                acc_a[g] = __builtin_amdgcn_mfma_f32_32x32x16_bf16(Aha, Bl, acc_a[g], 0,0,0);
                acc_a[g] = __builtin_amdgcn_mfma_f32_32x32x16_bf16(Aha, Bh, acc_a[g], 0,0,0);
                acc_b[g] = __builtin_amdgcn_mfma_f32_32x32x16_bf16(Alb, Bh, acc_b[g], 0,0,0);
                acc_b[g] = __builtin_amdgcn_mfma_f32_32x32x16_bf16(Ahb, Bl, acc_b[g], 0,0,0);
                acc_b[g] = __builtin_amdgcn_mfma_f32_32x32x16_bf16(Ahb, Bh, acc_b[g], 0,0,0);
            }
        }
        if (ch < 7) {
            __syncthreads();
            write_stage();                        // chunk ch+1 regs -> LDS (vmcnt waits auto)
            __syncthreads();
            if (ch < 6) load_stage(ch + 2);       // prefetch hides under next MFMA phase
        }
    }

    // ---- epilogue: theta/magnitude, transpose via LDS, x4 stores ----
    __syncthreads();
    float* conv_s  = (float*)SM;                 // 32 x 256 floats = 32 KB
    float* theta_s = conv_s + 32*PXT;            // 32 KB (total 64 KB <= 66.5 KB)
    const float eps = 1e-05f;
    const float PIf = 3.14159265358979323846f;

    #pragma unroll
    for (int g = 0; g < 2; g++) {
        const int pcol = wave*64 + g*32 + n;
        const int p = l0 + pcol;
        #pragma unroll
        for (int r = 0; r < 16; r++) {
            int row = (r & 3) + 8*(r >> 2) + 4*kh;
            float av = acc_a[g][r];
            float bv = acc_b[g][r];
            bool flag = (p < LL) &&
                        (fabsf(av) < 1.5e-4f || (bv < 1.05e-5f && bv > -2.05e-5f));
            unsigned long long m = __ballot(flag);
            if (m) {
                int leader = (int)__ffsll((long long)m) - 1;
                unsigned base = 0;
                if (lane == leader) base = atomicAdd(cnt, (unsigned)__popcll(m));
                base = __shfl(base, leader);
                if (flag) {
                    unsigned slot = base + (unsigned)__popcll(m & ((1ULL << lane) - 1ULL));
                    if (slot < cap)
                        wl[slot] = ((unsigned)(bat*LL + p) << 7) | (unsigned)(o0 + row);
                }
            }
            bool ag = av > 0.f, bg = bv > 0.f;
            bool eq = (ag == bg);
            float ratio = eq ? (bv / (av + eps)) : (av / (bv + eps));
            float at = atanf(ratio);
            if (!eq) at = -at;
            float peak = eq ? (ag ? PIf*0.5f : -PIf*0.5f) : (bg ? 0.0f : -PIf);
            float th = peak - at;
            conv_s[row*PXT + pcol]  = sinf(th)*av + cosf(th)*bv + sm_bias[row];
            theta_s[row*PXT + pcol] = th * (1.0f/PIf);
        }
    }
    __syncthreads();
    size_t obase = (size_t)bat * (2*COUT) * LL;
    #pragma unroll
    for (int i = 0; i < 8; i++) {
        int s = tid + 256*i;
        int row = s >> 6, seg = s & 63;
        int px0 = l0 + seg*4;
        if (px0 < LL)
            *(f32x4*)&out[obase + (size_t)(o0+row)*LL + px0] = *(const f32x4*)&conv_s[(row<<8) + (seg<<2)];
    }
    #pragma unroll
    for (int i = 0; i < 8; i++) {
        int s = tid + 256*i;
        int row = s >> 6, seg = s & 63;
        int px0 = l0 + seg*4;
        if (px0 < LL)
            *(f32x4*)&out[obase + (size_t)(COUT+o0+row)*LL + px0] = *(const f32x4*)&theta_s[(row<<8) + (seg<<2)];
    }
}

// ---------------- fp64 fixup for near-discontinuity elements ----------------
__global__ __launch_bounds__(256)
void fixup_kernel(const float* __restrict__ x, const float* __restrict__ w,
                  const double* __restrict__ csd, const float* __restrict__ bias,
                  const unsigned* __restrict__ cnt, const unsigned* __restrict__ wl,
                  unsigned cap, float* __restrict__ out) {
    const int lane   = threadIdx.x & 63;
    const int waveid = (blockIdx.x * 256 + threadIdx.x) >> 6;
    const int nwaves = gridDim.x * 4;
    unsigned nf = *cnt; if (nf > cap) nf = cap;
    const double PI = 3.14159265358979323846;

    for (unsigned u = waveid; u < nf; u += nwaves) {
        unsigned idx = wl[u];
        int oc = idx & 127;
        unsigned rest = idx >> 7;
        int bb_ = rest / LL;
        int l   = rest - bb_*LL;
        int yy  = l / WW;
        int xx  = l - yy*WW;
        const float* xb = x + (size_t)bb_ * CIN * LL;

        double pa = 0.0, pb = 0.0;
        #pragma unroll
        for (int k = 0; k < 9; k++) {
            int dy = k/3, dx = k - dy*3;
            int py = yy + dy - 1, px = xx + dx - 1;
            double pk = 0.0;
            if ((unsigned)py < HH && (unsigned)px < WW) {
                int base = py*WW + px;
                const float* wr = w + k*(COUT*CIN) + oc*CIN;
                int c = lane;
                pk  = (double)xb[(size_t)c*LL + base] * (double)wr[c];
                c = lane + 64;
                pk += (double)xb[(size_t)c*LL + base] * (double)wr[c];
            }
            pa += csd[k*COUT + oc] * pk;
            pb += csd[9*COUT + k*COUT + oc] * pk;
        }
        #pragma unroll
        for (int off = 32; off > 0; off >>= 1) {
            pa += __shfl_xor(pa, off, 64);
            pb += __shfl_xor(pb, off, 64);
        }
        if (lane == 0) {
            bool ag = pa > 0.0, bg = pb > 0.0;
            bool eq = (ag == bg);
            double th;
            if (eq) th = (ag ? PI*0.5 : -PI*0.5) - atan(pb / (pa + 1e-5));
            else    th = (bg ? 0.0 : -PI) + atan(pa / (pb + 1e-5));
            double o = sin(th)*pa + cos(th)*pb + (double)bias[oc];
            out[((size_t)bb_*(2*COUT) + oc) * LL + l]        = (float)o;
            out[((size_t)bb_*(2*COUT) + COUT + oc) * LL + l] = (float)(th / PI);
        }
    }
}

extern "C" void kernel_launch(void* const* d_in, const int* in_sizes, int n_in,
                              void* d_out, int out_size, void* d_ws, size_t ws_size,
                              hipStream_t stream) {
    const float* x    = (const float*)d_in[0];
    const float* w    = (const float*)d_in[1];
    const float* bk   = (const float*)d_in[2];
    const float* bias = (const float*)d_in[3];
    float* out = (float*)d_out;

    char* ws = (char*)d_ws;
    unsigned*       cnt = (unsigned*)ws;
    double*         csd = (double*)(ws + CSD_OFF);
    unsigned short* wsp = (unsigned short*)(ws + WSP_OFF);
    unsigned short* xt  = (unsigned short*)(ws + XT_OFF);
    unsigned*       wl  = (unsigned*)(ws + WL_OFF);
    unsigned cap = (ws_size > (size_t)WL_OFF + 4096) ? (unsigned)((ws_size - WL_OFF) / 4) : 0u;

    hipMemsetAsync(cnt, 0, 4, stream);
    hipLaunchKernelGGL(prep_csd_kernel, dim3(9),    dim3(256), 0, stream, bk, csd);
    hipLaunchKernelGGL(prep_w_kernel,   dim3(576),  dim3(256), 0, stream, w, csd, wsp);
    hipLaunchKernelGGL(prep_x_kernel,   dim3(1798), dim3(256), 0, stream, x, xt);
    hipLaunchKernelGGL(mfma_kernel,     dim3(NB*NPXT*4), dim3(256), 0, stream,
                       xt, wsp, bias, out, cnt, wl, cap);
    hipLaunchKernelGGL(fixup_kernel,    dim3(512),  dim3(256), 0, stream,
                       x, w, csd, bias, cnt, wl, cap, out);
}

// Round 2
// 335.189 us; speedup vs baseline: 1.3220x; 1.0085x over previous
//
#include <hip/hip_runtime.h>
#include <hip/hip_bf16.h>
#include <math.h>

#define NB   16
#define CIN  128
#define COUT 128
#define HH   56
#define WW   56
#define LL   3136

typedef __attribute__((ext_vector_type(8))) short short8;
typedef __attribute__((ext_vector_type(16))) float f32x16;
typedef __attribute__((ext_vector_type(4))) float f32x4;
typedef __attribute__((ext_vector_type(4))) unsigned int uint4v;

// ---- mfma geometry ----
#define PXT    256            // pixels per block (linear)
#define NPXT   13             // ceil(3136/256)
#define XC     58             // cols incl halo
#define XPLANE 7424           // ushorts per x plane (8 rows * 58 * 16)
#define XUSH   14848          // ushorts x total (hi+lo) = 29,696 B
#define XUNITS 1856           // 16B units in x region
#define XHALF  928            // units per plane
#define CPW    16             // weight row pitch (ushorts)
#define WS_TAP 1024           // ushorts per tap per plane (64 rows * 16)
#define WS_N   9216           // ushorts per plane (9 taps)
#define WBYTES 36864          // bytes per (ocb,cg) weight image

// xt layout: [cg 8][bat 16][plane 2][row 62][col 58][16ch] ushorts (halo zeroed)
#define XT_ROWS 62
#define XT_PLANE_USH (XT_ROWS*XC*16)   // 57536
#define XT_CG_STRIDE 3682304           // bytes per cg slab

// ---- workspace layout (bytes) ----
#define CSD_OFF 256
#define WSP_OFF 32768
#define XT_OFF  1212416
#define XT_SIZE 29458432
#define WL_OFF  (XT_OFF + XT_SIZE)     // needs ws_size >= ~31MB

// ---------------- prep: folded/split weights + fp64 cos/sin table ----------------
// wsp layout: [ocb 4][cg 8] images of WBYTES; image = [plane 2][tap 9][row 64][16 ush]
__global__ void prep_w_kernel(const float* __restrict__ w, const float* __restrict__ bk,
                              double* __restrict__ csd, unsigned short* __restrict__ wsp) {
    int i = blockIdx.x * 256 + threadIdx.x;
    if (i >= 9*COUT*CIN) return;
    int k = i / (COUT*CIN);
    int rem = i - k*(COUT*CIN);
    int oc = rem >> 7, c = rem & 127;
    double bkv = (double)bk[k*COUT + oc];
    double ck = cos(bkv), sk = sin(bkv);
    if (c == 0) {
        csd[k*COUT + oc]          = ck;
        csd[9*COUT + k*COUT + oc] = sk;
    }
    float wv = w[i];
    float fa = (float)(ck * (double)wv);
    float fb = (float)(sk * (double)wv);
    __hip_bfloat16 ah = __float2bfloat16(fa);
    __hip_bfloat16 al = __float2bfloat16(fa - __bfloat162float(ah));
    __hip_bfloat16 bh = __float2bfloat16(fb);
    __hip_bfloat16 bl = __float2bfloat16(fb - __bfloat162float(bh));
    int ocb = oc >> 5;
    int rowa = oc & 31, rowb = 32 + rowa;
    int cg = c >> 4, cp = c & 15;
    int sl = (((cp >> 3) ^ ((rowa >> 2) & 1)) << 3) | (cp & 7);   // xor-swizzled 8-slot
    size_t img = ((size_t)ocb*8 + cg) * (WBYTES/2);
    wsp[img + (size_t)k*WS_TAP + rowa*CPW + sl]        = *(unsigned short*)&ah;
    wsp[img + (size_t)k*WS_TAP + rowb*CPW + sl]        = *(unsigned short*)&bh;
    wsp[img + WS_N + (size_t)k*WS_TAP + rowa*CPW + sl] = *(unsigned short*)&al;
    wsp[img + WS_N + (size_t)k*WS_TAP + rowb*CPW + sl] = *(unsigned short*)&bl;
}

// ---------------- prep: x -> bf16 hi/lo transposed padded layout (vectorized) ----------------
// main part: 8cg*16bat*56rows*14 col-quads = 100352 threads; halo-zero part: 117760 threads
__global__ void prep_x_kernel(const float* __restrict__ x, unsigned short* __restrict__ xt) {
    int i = blockIdx.x * 256 + threadIdx.x;          // 852*256 = 218112 exact
    if (i < 100352) {
        int c4 = i % 14; int t = i / 14;
        int row1 = t % 56; t /= 56;
        int bat = t & 15, cg = t >> 4;
        const float* xp = x + ((size_t)(bat*CIN + cg*16))*LL + row1*WW + c4*4;
        unsigned short hi[4][16], lo[4][16];
        #pragma unroll
        for (int j = 0; j < 16; j++) {
            f32x4 v = *(const f32x4*)(xp + (size_t)j*LL);
            #pragma unroll
            for (int cc = 0; cc < 4; cc++) {
                float f = v[cc];
                __hip_bfloat16 h = __float2bfloat16(f);
                __hip_bfloat16 l = __float2bfloat16(f - __bfloat162float(h));
                hi[cc][j] = *(unsigned short*)&h;
                lo[cc][j] = *(unsigned short*)&l;
            }
        }
        size_t base = ((((size_t)cg*16 + bat)*2 + 0)*XT_ROWS + (row1+1))*XC + (c4*4 + 1);
        #pragma unroll
        for (int cc = 0; cc < 4; cc++) {
            unsigned short* dh = xt + (base + cc)*16;
            unsigned short* dl = dh + XT_PLANE_USH;
            *(uint4v*)dh       = *(const uint4v*)&hi[cc][0];
            *(uint4v*)(dh + 8) = *(const uint4v*)&hi[cc][8];
            *(uint4v*)dl       = *(const uint4v*)&lo[cc][0];
            *(uint4v*)(dl + 8) = *(const uint4v*)&lo[cc][8];
        }
    } else {
        int i2 = i - 100352;                          // < 117760
        int unit = i2 % 460; int t = i2 / 460;
        int pl = t & 1; t >>= 1;
        int bat = t & 15, cg = t >> 4;
        int row, c58;
        if (unit < 348) {                             // full-zero rows 0,57..61
            int zr = unit / 58; c58 = unit - zr*58;
            row = (zr == 0) ? 0 : (56 + zr);
        } else {                                      // halo cols of rows 1..56
            int u2 = unit - 348; row = 1 + (u2 >> 1); c58 = (u2 & 1) ? 57 : 0;
        }
        size_t base = ((((size_t)cg*16 + bat)*2 + pl)*XT_ROWS + row)*XC + c58;
        uint4v zz = {0u,0u,0u,0u};
        *(uint4v*)(xt + base*16)     = zz;
        *(uint4v*)(xt + base*16 + 8) = zz;
    }
}

// ---------------- main MFMA kernel ----------------
__global__ __launch_bounds__(256, 3)
void mfma_kernel(const unsigned short* __restrict__ xt, const unsigned short* __restrict__ wsp,
                 const float* __restrict__ bias, float* __restrict__ out,
                 unsigned* __restrict__ cnt, unsigned* __restrict__ wl, unsigned cap)
{
    __shared__ __align__(16) unsigned short SM[XUSH];    // x tile only: 29,696 B
    __shared__ float sm_bias[32];

    const int tid = threadIdx.x;
    // XCD-chunked bijective swizzle (832 % 8 == 0)
    int bid = blockIdx.x;
    int wk = (bid & 7) * (NB*NPXT*4/8) + (bid >> 3);
    const int ocb = wk & 3; wk >>= 2;
    const int pxt = wk % NPXT;
    const int bat = wk / NPXT;
    const int l0  = pxt * PXT;
    const int o0  = ocb * 32;
    const int yf  = l0 / WW;

    const int lane = tid & 63;
    const int n    = lane & 31;
    const int kh   = lane >> 5;
    const int wave = tid >> 6;

    if (tid < 32) sm_bias[tid] = bias[o0 + tid];

    // per-lane global source offsets for x staging (bytes within one cg-slab)
    unsigned xoff[8];
    #pragma unroll
    for (int k = 0; k < 8; k++) {
        int u = tid + 256*k;
        int uc = u < XUNITS ? u : XUNITS-1;
        int pl = uc >= XHALF ? 1 : 0;
        int rem = uc - pl*XHALF;
        int q  = rem >> 1;
        int hl = rem & 1;
        int hg = hl ^ ((q >> 2) & 1);        // inverse of read-side bank swizzle
        int r  = q / XC;
        int c  = q - r*XC;
        xoff[k] = (unsigned)((((bat*2 + pl)*XT_ROWS + (yf + r))*XC + c)*32 + hg*16);
    }

    // B-frag pixel slots (2 groups per wave)
    int q0g[2];
    #pragma unroll
    for (int g = 0; g < 2; g++) {
        int p  = l0 + wave*64 + g*32 + n;
        int pc = p < LL ? p : LL-1;
        int py = pc / WW, pxx = pc - py*WW;
        q0g[g] = (py - yf)*XC + pxx;
    }
    const int sw  = ((((n>>2)&1) ^ kh) << 3);
    const int iAa = n*CPW + sw;
    const int iAb = (32+n)*CPW + sw;

    f32x16 acc_a[2], acc_b[2];
    #pragma unroll
    for (int g = 0; g < 2; g++) {
        #pragma unroll
        for (int r = 0; r < 16; r++) { acc_a[g][r] = 0.f; acc_b[g][r] = 0.f; }
    }

    const char* xtB  = (const char*)xt;
    const char* wspB = (const char*)wsp + (size_t)ocb * (8*(size_t)WBYTES);

    // async x stage: linear LDS dest (wave-uniform base + lane*16), swizzle on source
    auto stage = [&](int chn) {
        const char* xp = xtB + (size_t)chn * XT_CG_STRIDE;
        #pragma unroll
        for (int k = 0; k < 7; k++) {
            __builtin_amdgcn_global_load_lds(
                (const __attribute__((address_space(1))) unsigned int*)(xp + xoff[k]),
                (__attribute__((address_space(3))) unsigned int*)&SM[(wave*64 + 256*k)*8],
                16, 0, 0);
        }
        if (wave == 0)
            __builtin_amdgcn_global_load_lds(
                (const __attribute__((address_space(1))) unsigned int*)(xp + xoff[7]),
                (__attribute__((address_space(3))) unsigned int*)&SM[1792*8],
                16, 0, 0);
    };

    // weight ring: depth-2 ping-pong, global->reg (L1/L2-resident images)
    short8 wbuf[2][4];
    auto ldw = [&](int chn, int tap, short8* dst) {
        const char* tp = wspB + (size_t)chn*WBYTES + tap*(WS_TAP*2);
        dst[0] = *(const short8*)(tp + iAa*2);
        dst[1] = *(const short8*)(tp + iAb*2);
        dst[2] = *(const short8*)(tp + 2*WS_N + iAa*2);
        dst[3] = *(const short8*)(tp + 2*WS_N + iAb*2);
    };

    // prologue: stage chunk 0 (async), prefetch taps 0,1 weights
    stage(0);
    ldw(0, 0, wbuf[0]);
    ldw(0, 1, wbuf[1]);
    __syncthreads();                       // vmcnt(0) drain precedes barrier

    #pragma unroll 1
    for (int ch = 0; ch < 8; ch++) {
        #pragma unroll
        for (int tap = 0; tap < 9; tap++) {
            const int ky = tap / 3, kx = tap - 3*ky;
            short8 Aha = wbuf[tap&1][0];
            short8 Ahb = wbuf[tap&1][1];
            short8 Ala = wbuf[tap&1][2];
            short8 Alb = wbuf[tap&1][3];
            if (tap < 7) ldw(ch, tap+2, wbuf[tap&1]);   // same-parity slot, freed above
            __builtin_amdgcn_s_setprio(1);
            #pragma unroll
            for (int g = 0; g < 2; g++) {
                int q  = q0g[g] + ky*XC + kx;
                int si = q*16 + ((kh ^ ((q>>2)&1)) << 3);
                short8 Bh = *(const short8*)&SM[si];
                short8 Bl = *(const short8*)&SM[XPLANE + si];
                acc_a[g] = __builtin_amdgcn_mfma_f32_32x32x16_bf16(Ala, Bh, acc_a[g], 0,0,0);
                acc_a[g] = __builtin_amdgcn_mfma_f32_32x32x16_bf16(Aha, Bl, acc_a[g], 0,0,0);
                acc_a[g] = __builtin_amdgcn_mfma_f32_32x32x16_bf16(Aha, Bh, acc_a[g], 0,0,0);
                acc_b[g] = __builtin_amdgcn_mfma_f32_32x32x16_bf16(Alb, Bh, acc_b[g], 0,0,0);
                acc_b[g] = __builtin_amdgcn_mfma_f32_32x32x16_bf16(Ahb, Bl, acc_b[g], 0,0,0);
                acc_b[g] = __builtin_amdgcn_mfma_f32_32x32x16_bf16(Ahb, Bh, acc_b[g], 0,0,0);
            }
            __builtin_amdgcn_s_setprio(0);
        }
        if (ch < 7) {
            ldw(ch+1, 0, wbuf[0]);          // cross-chunk weight prefetch (parity-safe)
            ldw(ch+1, 1, wbuf[1]);
            __syncthreads();                // readers done with SM
            stage(ch+1);                    // async refill
            __syncthreads();                // vmcnt(0) drain + visibility
        }
    }

    // ---- epilogue: theta/magnitude, direct coalesced stores (no LDS) ----
    const float eps = 1e-05f;
    const float PIf = 3.14159265358979323846f;
    size_t obase = (size_t)bat * (2*COUT) * LL;

    #pragma unroll
    for (int g = 0; g < 2; g++) {
        const int pcol = wave*64 + g*32 + n;
        const int p = l0 + pcol;
        #pragma unroll
        for (int r = 0; r < 16; r++) {
            int row = (r & 3) + 8*(r >> 2) + 4*kh;
            float av = acc_a[g][r];
            float bv = acc_b[g][r];
            bool flag = (p < LL) &&
                        (fabsf(av) < 1.5e-4f || (bv < 1.05e-5f && bv > -2.05e-5f));
            unsigned long long m = __ballot(flag);
            if (m) {
                int leader = (int)__ffsll((long long)m) - 1;
                unsigned base = 0;
                if (lane == leader) base = atomicAdd(cnt, (unsigned)__popcll(m));
                base = __shfl(base, leader);
                if (flag) {
                    unsigned slot = base + (unsigned)__popcll(m & ((1ULL << lane) - 1ULL));
                    if (slot < cap)
                        wl[slot] = ((unsigned)(bat*LL + p) << 7) | (unsigned)(o0 + row);
                }
            }
            bool ag = av > 0.f, bg = bv > 0.f;
            bool eq = (ag == bg);
            float ratio = eq ? (bv / (av + eps)) : (av / (bv + eps));
            float at = atanf(ratio);
            if (!eq) at = -at;
            float peak = eq ? (ag ? PIf*0.5f : -PIf*0.5f) : (bg ? 0.0f : -PIf);
            float th = peak - at;
            if (p < LL) {
                out[obase + (size_t)(o0+row)*LL + p]      = sinf(th)*av + cosf(th)*bv + sm_bias[row];
                out[obase + (size_t)(COUT+o0+row)*LL + p] = th * (1.0f/PIf);
            }
        }
    }
}

// ---------------- fp64 fixup for near-discontinuity elements ----------------
__global__ __launch_bounds__(256)
void fixup_kernel(const float* __restrict__ x, const float* __restrict__ w,
                  const double* __restrict__ csd, const float* __restrict__ bias,
                  const unsigned* __restrict__ cnt, const unsigned* __restrict__ wl,
                  unsigned cap, float* __restrict__ out) {
    const int lane   = threadIdx.x & 63;
    const int waveid = (blockIdx.x * 256 + threadIdx.x) >> 6;
    const int nwaves = gridDim.x * 4;
    unsigned nf = *cnt; if (nf > cap) nf = cap;
    const double PI = 3.14159265358979323846;

    for (unsigned u = waveid; u < nf; u += nwaves) {
        unsigned idx = wl[u];
        int oc = idx & 127;
        unsigned rest = idx >> 7;
        int bb_ = rest / LL;
        int l   = rest - bb_*LL;
        int yy  = l / WW;
        int xx  = l - yy*WW;
        const float* xb = x + (size_t)bb_ * CIN * LL;

        double pa = 0.0, pb = 0.0;
        #pragma unroll
        for (int k = 0; k < 9; k++) {
            int dy = k/3, dx = k - dy*3;
            int py = yy + dy - 1, px = xx + dx - 1;
            double pk = 0.0;
            if ((unsigned)py < HH && (unsigned)px < WW) {
                int base = py*WW + px;
                const float* wr = w + k*(COUT*CIN) + oc*CIN;
                int c = lane;
                pk  = (double)xb[(size_t)c*LL + base] * (double)wr[c];
                c = lane + 64;
                pk += (double)xb[(size_t)c*LL + base] * (double)wr[c];
            }
            pa += csd[k*COUT + oc] * pk;
            pb += csd[9*COUT + k*COUT + oc] * pk;
        }
        #pragma unroll
        for (int off = 32; off > 0; off >>= 1) {
            pa += __shfl_xor(pa, off, 64);
            pb += __shfl_xor(pb, off, 64);
        }
        if (lane == 0) {
            bool ag = pa > 0.0, bg = pb > 0.0;
            bool eq = (ag == bg);
            double th;
            if (eq) th = (ag ? PI*0.5 : -PI*0.5) - atan(pb / (pa + 1e-5));
            else    th = (bg ? 0.0 : -PI) + atan(pa / (pb + 1e-5));
            double o = sin(th)*pa + cos(th)*pb + (double)bias[oc];
            out[((size_t)bb_*(2*COUT) + oc) * LL + l]        = (float)o;
            out[((size_t)bb_*(2*COUT) + COUT + oc) * LL + l] = (float)(th / PI);
        }
    }
}

extern "C" void kernel_launch(void* const* d_in, const int* in_sizes, int n_in,
                              void* d_out, int out_size, void* d_ws, size_t ws_size,
                              hipStream_t stream) {
    const float* x    = (const float*)d_in[0];
    const float* w    = (const float*)d_in[1];
    const float* bk   = (const float*)d_in[2];
    const float* bias = (const float*)d_in[3];
    float* out = (float*)d_out;

    char* ws = (char*)d_ws;
    unsigned*       cnt = (unsigned*)ws;
    double*         csd = (double*)(ws + CSD_OFF);
    unsigned short* wsp = (unsigned short*)(ws + WSP_OFF);
    unsigned short* xt  = (unsigned short*)(ws + XT_OFF);
    unsigned*       wl  = (unsigned*)(ws + WL_OFF);
    unsigned cap = (ws_size > (size_t)WL_OFF + 4096) ? (unsigned)((ws_size - WL_OFF) / 4) : 0u;

    hipMemsetAsync(cnt, 0, 4, stream);
    hipLaunchKernelGGL(prep_w_kernel,   dim3(576),  dim3(256), 0, stream, w, bk, csd, wsp);
    hipLaunchKernelGGL(prep_x_kernel,   dim3(852),  dim3(256), 0, stream, x, xt);
    hipLaunchKernelGGL(mfma_kernel,     dim3(NB*NPXT*4), dim3(256), 0, stream,
                       xt, wsp, bias, out, cnt, wl, cap);
    hipLaunchKernelGGL(fixup_kernel,    dim3(512),  dim3(256), 0, stream,
                       x, w, csd, bias, cnt, wl, cap, out);
}